// Round 1
// 177.708 us; speedup vs baseline: 1.0469x; 1.0469x over previous
//
#include <hip/hip_runtime.h>
#include <stdint.h>

#define H_ 96
#define W_ 96
#define C_ 256
#define O_ 256
#define N_ 2
#define HW_ (H_*W_)          // 9216
#define M_ (N_*HW_)          // 18432
#define GK 2304              // C_*9

typedef __bf16 bf16x8 __attribute__((ext_vector_type(8)));
typedef float f32x4 __attribute__((ext_vector_type(4)));
typedef unsigned short us4 __attribute__((ext_vector_type(4)));
typedef unsigned short us8 __attribute__((ext_vector_type(8)));

__device__ __forceinline__ unsigned short f2bf(float f) {
  union { float f; unsigned int u; } v; v.f = f;
  unsigned int u = v.u;
  return (unsigned short)((u + 0x7fffu + ((u >> 16) & 1u)) >> 16);
}
__device__ __forceinline__ float bf2f(unsigned short h) {
  union { unsigned int u; float f; } v; v.u = ((unsigned int)h) << 16;
  return v.f;
}

// ---------------- Kernel 1: combined prep (unchanged).
__global__ __launch_bounds__(256) void k_pre(const float* __restrict__ x,
                                             const float* __restrict__ w_df,
                                             const float* __restrict__ w_tm,
                                             const float* __restrict__ w_tr,
                                             unsigned short* __restrict__ xt,
                                             unsigned short* __restrict__ wfrag,
                                             unsigned short* __restrict__ w6p) {
  const int b = blockIdx.x;
  const int tid = threadIdx.x;
  if (b < 288) {
    __shared__ unsigned short tile[128][130];
    const int pt = b % 72;          // 72 p-tiles of 128
    const int ch = (b / 72) & 1;    // 2 c-halves of 128
    const int n  = b / 144;
    const int p0 = pt * 128, c0 = ch * 128;
    const float* xp = x + (size_t)n * C_ * HW_;
    unsigned short* xtp = xt + (size_t)n * C_ * HW_;
    const int tx = tid & 31, ty = tid >> 5;  // 32 p-chunks x 8 c-rows
#pragma unroll
    for (int pass = 0; pass < 16; pass++) {
      const int c = pass * 8 + ty;
      const f32x4 v = *(const f32x4*)(xp + (size_t)(c0 + c) * HW_ + p0 + tx * 4);
#pragma unroll
      for (int i = 0; i < 4; i++) tile[tx * 4 + i][c] = f2bf(v[i]);
    }
    __syncthreads();
    const int wave = tid >> 6, lane = tid & 63;
    const int l32 = lane & 31, ph = lane >> 5;
#pragma unroll
    for (int pass = 0; pass < 16; pass++) {
      const int p = pass * 8 + wave * 2 + ph;
      us4 v;
#pragma unroll
      for (int i = 0; i < 4; i++) v[i] = tile[p][l32 * 4 + i];
      *(us4*)(xtp + (size_t)(p0 + p) * C_ + c0 + l32 * 4) = v;
    }
  } else if (b < 576) {
    const int base = (b - 288) * 2048 + tid * 8;  // < 589824
    const int l  = (base >> 3) & 63;
    const int g  = (base >> 9) & 15;
    const int ks = (base >> 13) & 7;
    const int t  = base >> 16;
    const int o  = g * 16 + (l & 15);
    const int c  = ks * 32 + (l >> 4) * 8;
    us8 res;
#pragma unroll
    for (int j = 0; j < 8; j++) res[j] = f2bf(w_df[(size_t)(o * 256 + c + j) * 9 + t]);
    *(us8*)(wfrag + base) = res;
  } else {
    int idx = (b - 576) * 256 + tid;   // < 9*16*256 = 36864
    int t = idx >> 12;
    int r = idx & 4095;
    int j = r >> 8;
    int c = r & 255;
    float v = 0.f;
    if (j < 4) v = w_tm[(size_t)(j * C_ + c) * 9 + t];
    else if (j < 6) v = w_tr[(size_t)((j - 4) * C_ + c) * 9 + t];
    w6p[idx] = f2bf(v);
  }
}

// ---------------- Kernel 2: FUSED offsets + sample + GEMM + BN + res + ReLU.
// v2: 32m x 256o blocks (grid 576), wave-tile 32m x 64o -> each bv fragment
// feeds 2 MFMAs and total Wfrag streaming halves (1.33GB -> 0.66GB).
// ONE barrier per tap (As double-buffered: the rewrite of As[b] happens
// after the NEXT barrier, which orders all reads of As[b]).
// bv loads hoisted BEFORE the barrier so the mandatory vmcnt(0) drain at
// s_barrier overlaps bv's L2 latency with the lerp VALU phase.
// Corner prefetch issued right after the barrier (before the bn stream) so
// its one-time in-order vmcnt coupling is paid once per tap, overlapped
// with ks0's MFMAs.
__global__ __launch_bounds__(256, 3) void k_fused(const unsigned short* __restrict__ xt,
                                                  const unsigned short* __restrict__ Wfrag,
                                                  const unsigned short* __restrict__ w6p,
                                                  const float* __restrict__ b_tm,
                                                  const float* __restrict__ b_tr,
                                                  const float* __restrict__ xres,
                                                  const float* __restrict__ gamma,
                                                  const float* __restrict__ beta,
                                                  const float* __restrict__ mean,
                                                  const float* __restrict__ var,
                                                  float* __restrict__ out) {
  __shared__ unsigned short As[2][32 * 256] __attribute__((aligned(16)));  // 32KB
  __shared__ float sred[4][16][8];
  __shared__ float coords_s[32][9][2];
  const int tid = threadIdx.x;
  const int wave = tid >> 6, lane = tid & 63;
  const int row = lane & 15, quad = lane >> 4;
  const int bm = (blockIdx.x & 7) * 72 + (blockIdx.x >> 3);  // XCD m-band swizzle (576=8*72)
  const int m0 = bm * 32;
  const int n = m0 / HW_;   // 32 | 9216: tile never crosses n
  const int sr = tid >> 4;  // staging row 0..15 (also handles row sr+16)
  const int cg = tid & 15;  // staging 16-channel group

  // ---- Prologue: offset conv for the 32-m strip ----
  // waves 0,1 -> rows 0..15; waves 2,3 -> rows 16..31; each wave one 128-ch half.
  {
    const int hw0 = m0 - n * HW_;
    const int h = hw0 / W_;
    const int w0 = hw0 - h * W_;  // multiple of 32 (32 | 96)
    const int rh = wave >> 1;     // row half
    const int cq = (wave & 1) * 128;
    f32x4 oacc = {0.f, 0.f, 0.f, 0.f};
    const bf16x8 zero8 = {};
#pragma unroll
    for (int t = 0; t < 9; t++) {
      const int ty = t / 3, tx = t % 3;
      const int y = h + ty - 1;
      if (y < 0 || y >= H_) continue;  // wave-uniform
      const int xx = w0 + rh * 16 + row + tx - 1;
      const bool valid = (xx >= 0) && (xx < W_);
      const int xc = min(max(xx, 0), W_ - 1);
      const unsigned short* arow =
          xt + (size_t)((n * H_ + y) * W_ + xc) * C_ + cq + quad * 8;
      const unsigned short* brow =
          w6p + (size_t)(t * 16 + row) * C_ + cq + quad * 8;
#pragma unroll
      for (int ks = 0; ks < 4; ks++) {
        bf16x8 av = *(const bf16x8*)(const void*)(arow + ks * 32);
        if (!valid) av = zero8;
        bf16x8 bv = *(const bf16x8*)(const void*)(brow + ks * 32);
        oacc = __builtin_amdgcn_mfma_f32_16x16x32_bf16(av, bv, oacc, 0, 0, 0);
      }
    }
    if (row < 6) {
#pragma unroll
      for (int r = 0; r < 4; r++) sred[wave][quad * 4 + r][row] = oacc[r];
    }
  }
  __syncthreads();
  if (wave < 2 && lane < 16) {
    const int rg = wave * 16 + lane;  // global row 0..31
    const int hwm = m0 + rg - n * HW_;
    const int h = hwm / W_, w = hwm - h * W_;
    float a[6];
#pragma unroll
    for (int j = 0; j < 6; j++)
      a[j] = sred[wave * 2][lane][j] + sred[wave * 2 + 1][lane][j];
    const float tm0 = a[0] + b_tm[0];
    const float tm1 = a[1] + b_tm[1];
    const float tm2 = a[2] + b_tm[2];
    const float tm3 = a[3] + b_tm[3];
    const float tr0 = a[4] + b_tr[0];
    const float tr1 = a[5] + b_tr[1];
#pragma unroll
    for (int t = 0; t < 9; t++) {
      const float ry = (float)(t / 3) - 1.f;
      const float rx = (float)(t % 3) - 1.f;
      coords_s[rg][t][0] = (float)h + tr0 + tm0 * ry + tm1 * rx;
      coords_s[rg][t][1] = (float)w + tr1 + tm2 * ry + tm3 * rx;
    }
  }
  __syncthreads();

  // ---- Main loop over 9 taps ----
  f32x4 acc0[4] = {}, acc1[4] = {};
  float cwA[4], cwB[4];
  int cbA[4], cbB[4];
  us8 uA0[4], uA1[4], uB0[4], uB1[4];

#define PREP1(TAP, R, CW, CB)                                                  \
  {                                                                            \
    const float py = coords_s[R][TAP][0];                                      \
    const float px = coords_s[R][TAP][1];                                      \
    const float fy = floorf(py), fx = floorf(px);                              \
    const float wy = py - fy, wx = px - fx;                                    \
    const int y0 = (int)fy, x0 = (int)fx;                                      \
    const int y1 = y0 + 1, x1 = x0 + 1;                                        \
    const float vy0 = (y0 >= 0 && y0 < H_) ? 1.f : 0.f;                        \
    const float vy1 = (y1 >= 0 && y1 < H_) ? 1.f : 0.f;                        \
    const float vx0 = (x0 >= 0 && x0 < W_) ? 1.f : 0.f;                        \
    const float vx1 = (x1 >= 0 && x1 < W_) ? 1.f : 0.f;                        \
    CW[0] = (1.f - wy) * (1.f - wx) * vy0 * vx0;                               \
    CW[1] = (1.f - wy) * wx * vy0 * vx1;                                       \
    CW[2] = wy * (1.f - wx) * vy1 * vx0;                                       \
    CW[3] = wy * wx * vy1 * vx1;                                               \
    const int cy0 = min(max(y0, 0), H_ - 1), cy1 = min(max(y1, 0), H_ - 1);    \
    const int cx0 = min(max(x0, 0), W_ - 1), cx1 = min(max(x1, 0), W_ - 1);    \
    CB[0] = ((n * H_ + cy0) * W_ + cx0) * C_;                                  \
    CB[1] = ((n * H_ + cy0) * W_ + cx1) * C_;                                  \
    CB[2] = ((n * H_ + cy1) * W_ + cx0) * C_;                                  \
    CB[3] = ((n * H_ + cy1) * W_ + cx1) * C_;                                  \
  }

#define LOADC1(CB, U0, U1)                                                     \
  {                                                                            \
    const int cc = cg * 16;                                                    \
    U0[0] = *(const us8*)(xt + CB[0] + cc); U1[0] = *(const us8*)(xt + CB[0] + cc + 8); \
    U0[1] = *(const us8*)(xt + CB[1] + cc); U1[1] = *(const us8*)(xt + CB[1] + cc + 8); \
    U0[2] = *(const us8*)(xt + CB[2] + cc); U1[2] = *(const us8*)(xt + CB[2] + cc + 8); \
    U0[3] = *(const us8*)(xt + CB[3] + cc); U1[3] = *(const us8*)(xt + CB[3] + cc + 8); \
  }

#define LERP8(DST, U, CW)                                                      \
  {                                                                            \
    _Pragma("unroll")                                                          \
    for (int e = 0; e < 8; e++)                                                \
      DST[e] = f2bf(CW[0] * bf2f(U[0][e]) + CW[1] * bf2f(U[1][e]) +            \
                    CW[2] * bf2f(U[2][e]) + CW[3] * bf2f(U[3][e]));            \
  }

  PREP1(0, sr, cwA, cbA);
  PREP1(0, sr + 16, cwB, cbB);
  LOADC1(cbA, uA0, uA1);
  LOADC1(cbB, uB0, uB1);

  for (int tap = 0; tap < 9; tap++) {
    unsigned short* __restrict__ asb = As[tap & 1];
    // lerp both rows into As[buf] (swizzled slots: slot = (q&24)|((q^row)&7);
    // rows r and r+16 share slots since (r&7) is unchanged by +16)
    {
      const int q0 = cg * 2, q1 = cg * 2 + 1;
      const int s0 = (q0 & 24) | ((q0 ^ sr) & 7);
      const int s1 = (q1 & 24) | ((q1 ^ sr) & 7);
      us8 r0, r1;
      LERP8(r0, uA0, cwA);
      LERP8(r1, uA1, cwA);
      *(us8*)(void*)&asb[sr * 256 + s0 * 8] = r0;
      *(us8*)(void*)&asb[sr * 256 + s1 * 8] = r1;
      LERP8(r0, uB0, cwB);
      LERP8(r1, uB1, cwB);
      *(us8*)(void*)&asb[(sr + 16) * 256 + s0 * 8] = r0;
      *(us8*)(void*)&asb[(sr + 16) * 256 + s1 * 8] = r1;
    }

    // bv loads issued BEFORE the barrier: the s_barrier's vmcnt(0) drain
    // then overlaps bv's L2 latency with other waves' lerp, and the first
    // MFMA after the barrier has bv already in registers.
    const unsigned short* wfTap =
        Wfrag + (size_t)(tap * 8) * 8192 + wave * 2048 + lane * 8;
    bf16x8 bv[4];
#pragma unroll
    for (int ot = 0; ot < 4; ot++) bv[ot] = *(const bf16x8*)(const void*)(wfTap + ot * 512);

    __syncthreads();  // ONE barrier per tap

    if (tap < 8) {  // corner prefetch for tap+1: issued before the bn stream
      PREP1(tap + 1, sr, cwA, cbA);
      PREP1(tap + 1, sr + 16, cwB, cbB);
      LOADC1(cbA, uA0, uA1);
      LOADC1(cbB, uB0, uB1);
    }

#pragma unroll
    for (int ks = 0; ks < 8; ks++) {
      const int q = ks * 4 + quad;
      const int slot = (q & 24) | ((q ^ row) & 7);
      const bf16x8 av0 = *(const bf16x8*)(const void*)&asb[row * 256 + slot * 8];
      const bf16x8 av1 = *(const bf16x8*)(const void*)&asb[(row + 16) * 256 + slot * 8];
      bf16x8 bn[4];
      if (ks < 7) {
        const unsigned short* wfn = wfTap + (size_t)(ks + 1) * 8192;
#pragma unroll
        for (int ot = 0; ot < 4; ot++) bn[ot] = *(const bf16x8*)(const void*)(wfn + ot * 512);
      }
#pragma unroll
      for (int ot = 0; ot < 4; ot++)
        acc0[ot] = __builtin_amdgcn_mfma_f32_16x16x32_bf16(av0, bv[ot], acc0[ot], 0, 0, 0);
#pragma unroll
      for (int ot = 0; ot < 4; ot++)
        acc1[ot] = __builtin_amdgcn_mfma_f32_16x16x32_bf16(av1, bv[ot], acc1[ot], 0, 0, 0);
      if (ks < 7) {
#pragma unroll
        for (int ot = 0; ot < 4; ot++) bv[ot] = bn[ot];
      }
    }
    // NO trailing barrier: As is double-buffered. The next write to As[tap&1]
    // (lerp of tap+2) happens after barrier(tap+1), and every wave's reads of
    // As[tap&1] above precede its arrival at barrier(tap+1).
  }

  // ---- Epilogue: BN + residual + ReLU, float4 rows (both m-halves) ----
  const int hwb = m0 - n * HW_ + quad * 4;
#pragma unroll
  for (int ot = 0; ot < 4; ot++) {
    const int o = wave * 64 + ot * 16 + row;
    const float sc = rsqrtf(var[o] + 1e-5f) * gamma[o];
    const float bi = beta[o] - mean[o] * sc;
    const size_t ob0 = (size_t)(n * O_ + o) * HW_ + hwb;
    f32x4 rv = *(const f32x4*)(xres + ob0);
    f32x4 ov;
#pragma unroll
    for (int r = 0; r < 4; r++) ov[r] = fmaxf(acc0[ot][r] * sc + bi + rv[r], 0.f);
    *(f32x4*)(out + ob0) = ov;
    const size_t ob1 = ob0 + 16;  // rows 16..31, same h-strip
    rv = *(const f32x4*)(xres + ob1);
#pragma unroll
    for (int r = 0; r < 4; r++) ov[r] = fmaxf(acc1[ot][r] * sc + bi + rv[r], 0.f);
    *(f32x4*)(out + ob1) = ov;
  }
}

extern "C" void kernel_launch(void* const* d_in, const int* in_sizes, int n_in,
                              void* d_out, int out_size, void* d_ws, size_t ws_size,
                              hipStream_t stream) {
  const float* x     = (const float*)d_in[0];
  const float* w_tm  = (const float*)d_in[2];
  const float* b_tm  = (const float*)d_in[3];
  const float* w_tr  = (const float*)d_in[4];
  const float* b_tr  = (const float*)d_in[5];
  const float* w_df  = (const float*)d_in[6];
  const float* gamma = (const float*)d_in[7];
  const float* beta  = (const float*)d_in[8];
  const float* mean  = (const float*)d_in[9];
  const float* var   = (const float*)d_in[10];
  float* out = (float*)d_out;

  char* ws = (char*)d_ws;
  unsigned short* xt    = (unsigned short*)(ws);                       //  9,437,184 B
  unsigned short* wfrag = (unsigned short*)(ws + 9437184);             //  1,179,648 B
  unsigned short* w6p   = (unsigned short*)(ws + 9437184 + 1179648);   //     73,728 B

  k_pre<<<720, 256, 0, stream>>>(x, w_df, w_tm, w_tr, xt, wfrag, w6p);
  k_fused<<<576, 256, 0, stream>>>(xt, wfrag, w6p, b_tm, b_tr, x,
                                   gamma, beta, mean, var, out);
}

// Round 2
// 177.092 us; speedup vs baseline: 1.0505x; 1.0035x over previous
//
#include <hip/hip_runtime.h>
#include <stdint.h>

#define H_ 96
#define W_ 96
#define C_ 256
#define O_ 256
#define N_ 2
#define HW_ (H_*W_)          // 9216
#define M_ (N_*HW_)          // 18432
#define GK 2304              // C_*9

typedef __bf16 bf16x8 __attribute__((ext_vector_type(8)));
typedef float f32x4 __attribute__((ext_vector_type(4)));
typedef float f32x2 __attribute__((ext_vector_type(2)));
typedef unsigned short us4 __attribute__((ext_vector_type(4)));
typedef unsigned short us8 __attribute__((ext_vector_type(8)));

__device__ __forceinline__ unsigned short f2bf(float f) {
  union { float f; unsigned int u; } v; v.f = f;
  unsigned int u = v.u;
  return (unsigned short)((u + 0x7fffu + ((u >> 16) & 1u)) >> 16);
}
__device__ __forceinline__ float bf2f(unsigned short h) {
  union { unsigned int u; float f; } v; v.u = ((unsigned int)h) << 16;
  return v.f;
}
// two packed bf16 (one u32) -> two f32
__device__ __forceinline__ f32x2 bfpair(unsigned int a) {
  union { unsigned int u; float f; } lo, hi;
  lo.u = a << 16;
  hi.u = a & 0xffff0000u;
  f32x2 r; r[0] = lo.f; r[1] = hi.f;
  return r;
}

// ---------------- Kernel 1: combined prep (unchanged).
__global__ __launch_bounds__(256) void k_pre(const float* __restrict__ x,
                                             const float* __restrict__ w_df,
                                             const float* __restrict__ w_tm,
                                             const float* __restrict__ w_tr,
                                             unsigned short* __restrict__ xt,
                                             unsigned short* __restrict__ wfrag,
                                             unsigned short* __restrict__ w6p) {
  const int b = blockIdx.x;
  const int tid = threadIdx.x;
  if (b < 288) {
    __shared__ unsigned short tile[128][130];
    const int pt = b % 72;          // 72 p-tiles of 128
    const int ch = (b / 72) & 1;    // 2 c-halves of 128
    const int n  = b / 144;
    const int p0 = pt * 128, c0 = ch * 128;
    const float* xp = x + (size_t)n * C_ * HW_;
    unsigned short* xtp = xt + (size_t)n * C_ * HW_;
    const int tx = tid & 31, ty = tid >> 5;  // 32 p-chunks x 8 c-rows
#pragma unroll
    for (int pass = 0; pass < 16; pass++) {
      const int c = pass * 8 + ty;
      const f32x4 v = *(const f32x4*)(xp + (size_t)(c0 + c) * HW_ + p0 + tx * 4);
#pragma unroll
      for (int i = 0; i < 4; i++) tile[tx * 4 + i][c] = f2bf(v[i]);
    }
    __syncthreads();
    const int wave = tid >> 6, lane = tid & 63;
    const int l32 = lane & 31, ph = lane >> 5;
#pragma unroll
    for (int pass = 0; pass < 16; pass++) {
      const int p = pass * 8 + wave * 2 + ph;
      us4 v;
#pragma unroll
      for (int i = 0; i < 4; i++) v[i] = tile[p][l32 * 4 + i];
      *(us4*)(xtp + (size_t)(p0 + p) * C_ + c0 + l32 * 4) = v;
    }
  } else if (b < 576) {
    const int base = (b - 288) * 2048 + tid * 8;  // < 589824
    const int l  = (base >> 3) & 63;
    const int g  = (base >> 9) & 15;
    const int ks = (base >> 13) & 7;
    const int t  = base >> 16;
    const int o  = g * 16 + (l & 15);
    const int c  = ks * 32 + (l >> 4) * 8;
    us8 res;
#pragma unroll
    for (int j = 0; j < 8; j++) res[j] = f2bf(w_df[(size_t)(o * 256 + c + j) * 9 + t]);
    *(us8*)(wfrag + base) = res;
  } else {
    int idx = (b - 576) * 256 + tid;   // < 9*16*256 = 36864
    int t = idx >> 12;
    int r = idx & 4095;
    int j = r >> 8;
    int c = r & 255;
    float v = 0.f;
    if (j < 4) v = w_tm[(size_t)(j * C_ + c) * 9 + t];
    else if (j < 6) v = w_tr[(size_t)((j - 4) * C_ + c) * 9 + t];
    w6p[idx] = f2bf(v);
  }
}

// ---------------- Kernel 2: FUSED offsets + sample + GEMM + BN + res + ReLU.
// v3: 512 threads / 8 waves per block, 32m x 256o tile (grid 576 unchanged),
// wave-tile 32m x 32o. Doubles resident waves (2.25 -> 4.5 per SIMD) at v2's
// traffic efficiency: bv reuse still 2 MFMA/fragment, Wfrag stream unchanged.
// Each staging thread owns ONE row (sr = tid>>4 in 0..31): corner regs halve,
// lerp per thread halves. Lerp rewritten with f32x2 (v_pk_fma_f32) and native
// __bf16 casts (v_cvt_pk_bf16_f32, RTNE - identical rounding to manual f2bf).
// Still ONE barrier per tap (As double-buffered, same ordering proof as v2).
__global__ __launch_bounds__(512, 4) void k_fused(const unsigned short* __restrict__ xt,
                                                  const unsigned short* __restrict__ Wfrag,
                                                  const unsigned short* __restrict__ w6p,
                                                  const float* __restrict__ b_tm,
                                                  const float* __restrict__ b_tr,
                                                  const float* __restrict__ xres,
                                                  const float* __restrict__ gamma,
                                                  const float* __restrict__ beta,
                                                  const float* __restrict__ mean,
                                                  const float* __restrict__ var,
                                                  float* __restrict__ out) {
  __shared__ unsigned short As[2][32 * 256] __attribute__((aligned(16)));  // 32KB
  __shared__ float sred[8][16][8];
  __shared__ float coords_s[32][9][2];
  const int tid = threadIdx.x;
  const int wave = tid >> 6, lane = tid & 63;
  const int row = lane & 15, quad = lane >> 4;
  const int bm = (blockIdx.x & 7) * 72 + (blockIdx.x >> 3);  // XCD m-band swizzle
  const int m0 = bm * 32;
  const int n = m0 / HW_;   // 32 | 9216: tile never crosses n
  const int sr = tid >> 4;  // staging row 0..31 (one row per thread)
  const int cg = tid & 15;  // staging 16-channel group

  // ---- Prologue: offset conv for the 32-m strip ----
  // waves 0-3 -> rows 0..15, waves 4-7 -> rows 16..31; each wave a 64-ch quarter.
  {
    const int hw0 = m0 - n * HW_;
    const int h = hw0 / W_;
    const int w0 = hw0 - h * W_;  // multiple of 32 (32 | 96)
    const int rh = wave >> 2;     // row half
    const int cq = (wave & 3) * 64;
    f32x4 oacc = {0.f, 0.f, 0.f, 0.f};
    const bf16x8 zero8 = {};
#pragma unroll
    for (int t = 0; t < 9; t++) {
      const int ty = t / 3, tx = t % 3;
      const int y = h + ty - 1;
      if (y < 0 || y >= H_) continue;  // wave-uniform
      const int xx = w0 + rh * 16 + row + tx - 1;
      const bool valid = (xx >= 0) && (xx < W_);
      const int xc = min(max(xx, 0), W_ - 1);
      const unsigned short* arow =
          xt + (size_t)((n * H_ + y) * W_ + xc) * C_ + cq + quad * 8;
      const unsigned short* brow =
          w6p + (size_t)(t * 16 + row) * C_ + cq + quad * 8;
#pragma unroll
      for (int ks = 0; ks < 2; ks++) {
        bf16x8 av = *(const bf16x8*)(const void*)(arow + ks * 32);
        if (!valid) av = zero8;
        bf16x8 bv = *(const bf16x8*)(const void*)(brow + ks * 32);
        oacc = __builtin_amdgcn_mfma_f32_16x16x32_bf16(av, bv, oacc, 0, 0, 0);
      }
    }
    if (row < 6) {
#pragma unroll
      for (int r = 0; r < 4; r++) sred[wave][quad * 4 + r][row] = oacc[r];
    }
  }
  __syncthreads();
  if (wave < 2 && lane < 16) {
    const int rg = wave * 16 + lane;  // global row 0..31
    const int hwm = m0 + rg - n * HW_;
    const int h = hwm / W_, w = hwm - h * W_;
    float a[6];
#pragma unroll
    for (int j = 0; j < 6; j++)
      a[j] = sred[wave * 4 + 0][lane][j] + sred[wave * 4 + 1][lane][j] +
             sred[wave * 4 + 2][lane][j] + sred[wave * 4 + 3][lane][j];
    const float tm0 = a[0] + b_tm[0];
    const float tm1 = a[1] + b_tm[1];
    const float tm2 = a[2] + b_tm[2];
    const float tm3 = a[3] + b_tm[3];
    const float tr0 = a[4] + b_tr[0];
    const float tr1 = a[5] + b_tr[1];
#pragma unroll
    for (int t = 0; t < 9; t++) {
      const float ry = (float)(t / 3) - 1.f;
      const float rx = (float)(t % 3) - 1.f;
      coords_s[rg][t][0] = (float)h + tr0 + tm0 * ry + tm1 * rx;
      coords_s[rg][t][1] = (float)w + tr1 + tm2 * ry + tm3 * rx;
    }
  }
  __syncthreads();

  // ---- Main loop over 9 taps ----
  f32x4 acc0[2] = {}, acc1[2] = {};
  float cw[4];
  int cb[4];
  us8 u0[4], u1[4];  // corner data for row sr, channels cg*16..+7 and +8..+15

#define PREP1(TAP)                                                             \
  {                                                                            \
    const float py = coords_s[sr][TAP][0];                                     \
    const float px = coords_s[sr][TAP][1];                                     \
    const float fy = floorf(py), fx = floorf(px);                              \
    const float wy = py - fy, wx = px - fx;                                    \
    const int y0 = (int)fy, x0 = (int)fx;                                      \
    const int y1 = y0 + 1, x1 = x0 + 1;                                        \
    const float vy0 = (y0 >= 0 && y0 < H_) ? 1.f : 0.f;                        \
    const float vy1 = (y1 >= 0 && y1 < H_) ? 1.f : 0.f;                        \
    const float vx0 = (x0 >= 0 && x0 < W_) ? 1.f : 0.f;                        \
    const float vx1 = (x1 >= 0 && x1 < W_) ? 1.f : 0.f;                        \
    cw[0] = (1.f - wy) * (1.f - wx) * vy0 * vx0;                               \
    cw[1] = (1.f - wy) * wx * vy0 * vx1;                                       \
    cw[2] = wy * (1.f - wx) * vy1 * vx0;                                       \
    cw[3] = wy * wx * vy1 * vx1;                                               \
    const int cy0 = min(max(y0, 0), H_ - 1), cy1 = min(max(y1, 0), H_ - 1);    \
    const int cx0 = min(max(x0, 0), W_ - 1), cx1 = min(max(x1, 0), W_ - 1);    \
    cb[0] = ((n * H_ + cy0) * W_ + cx0) * C_;                                  \
    cb[1] = ((n * H_ + cy0) * W_ + cx1) * C_;                                  \
    cb[2] = ((n * H_ + cy1) * W_ + cx0) * C_;                                  \
    cb[3] = ((n * H_ + cy1) * W_ + cx1) * C_;                                  \
  }

#define LOADC1()                                                               \
  {                                                                            \
    const int cc = cg * 16;                                                    \
    u0[0] = *(const us8*)(xt + cb[0] + cc); u1[0] = *(const us8*)(xt + cb[0] + cc + 8); \
    u0[1] = *(const us8*)(xt + cb[1] + cc); u1[1] = *(const us8*)(xt + cb[1] + cc + 8); \
    u0[2] = *(const us8*)(xt + cb[2] + cc); u1[2] = *(const us8*)(xt + cb[2] + cc + 8); \
    u0[3] = *(const us8*)(xt + cb[3] + cc); u1[3] = *(const us8*)(xt + cb[3] + cc + 8); \
  }

  // packed-f32 lerp of one us8 (4 bf16-pairs) -> bf16x8 via RTNE cvt
#define LERP8V(DST, U)                                                         \
  {                                                                            \
    const unsigned int* a0 = (const unsigned int*)&U[0];                       \
    const unsigned int* a1 = (const unsigned int*)&U[1];                       \
    const unsigned int* a2 = (const unsigned int*)&U[2];                       \
    const unsigned int* a3 = (const unsigned int*)&U[3];                       \
    _Pragma("unroll")                                                          \
    for (int p = 0; p < 4; p++) {                                              \
      f32x2 acc = bfpair(a0[p]) * cw[0] + bfpair(a1[p]) * cw[1] +              \
                  bfpair(a2[p]) * cw[2] + bfpair(a3[p]) * cw[3];               \
      DST[p * 2]     = (__bf16)acc[0];                                         \
      DST[p * 2 + 1] = (__bf16)acc[1];                                         \
    }                                                                          \
  }

  PREP1(0);
  LOADC1();

  for (int tap = 0; tap < 9; tap++) {
    unsigned short* __restrict__ asb = As[tap & 1];
    // lerp row sr into As[buf] (swizzled slots: slot = (q&24)|((q^sr)&7);
    // (r+16)&7 == r&7 so read side may use row or row+16 equivalently)
    {
      const int q0 = cg * 2, q1 = cg * 2 + 1;
      const int s0 = (q0 & 24) | ((q0 ^ sr) & 7);
      const int s1 = (q1 & 24) | ((q1 ^ sr) & 7);
      bf16x8 r0, r1;
      LERP8V(r0, u0);
      LERP8V(r1, u1);
      *(bf16x8*)(void*)&asb[sr * 256 + s0 * 8] = r0;
      *(bf16x8*)(void*)&asb[sr * 256 + s1 * 8] = r1;
    }

    // bv loads issued BEFORE the barrier: the s_barrier vmcnt drain overlaps
    // bv's L2 latency with other waves' lerp.
    const unsigned short* wfTap =
        Wfrag + (size_t)(tap * 8) * 8192 + wave * 1024 + lane * 8;
    bf16x8 bv[2];
#pragma unroll
    for (int ot = 0; ot < 2; ot++) bv[ot] = *(const bf16x8*)(const void*)(wfTap + ot * 512);

    __syncthreads();  // ONE barrier per tap

    if (tap < 8) {  // corner prefetch for tap+1, overlapped with the bn stream
      PREP1(tap + 1);
      LOADC1();
    }

#pragma unroll
    for (int ks = 0; ks < 8; ks++) {
      const int q = ks * 4 + quad;
      const int slot = (q & 24) | ((q ^ row) & 7);
      const bf16x8 av0 = *(const bf16x8*)(const void*)&asb[row * 256 + slot * 8];
      const bf16x8 av1 = *(const bf16x8*)(const void*)&asb[(row + 16) * 256 + slot * 8];
      bf16x8 bn[2];
      if (ks < 7) {
        const unsigned short* wfn = wfTap + (size_t)(ks + 1) * 8192;
#pragma unroll
        for (int ot = 0; ot < 2; ot++) bn[ot] = *(const bf16x8*)(const void*)(wfn + ot * 512);
      }
#pragma unroll
      for (int ot = 0; ot < 2; ot++)
        acc0[ot] = __builtin_amdgcn_mfma_f32_16x16x32_bf16(av0, bv[ot], acc0[ot], 0, 0, 0);
#pragma unroll
      for (int ot = 0; ot < 2; ot++)
        acc1[ot] = __builtin_amdgcn_mfma_f32_16x16x32_bf16(av1, bv[ot], acc1[ot], 0, 0, 0);
      if (ks < 7) {
#pragma unroll
        for (int ot = 0; ot < 2; ot++) bv[ot] = bn[ot];
      }
    }
    // NO trailing barrier: As double-buffered; next write to As[tap&1] happens
    // after barrier(tap+1), which orders all reads of As[tap&1].
  }

  // ---- Epilogue: BN + residual + ReLU, float4 rows (both m-halves) ----
  const int hwb = m0 - n * HW_ + quad * 4;
#pragma unroll
  for (int ot = 0; ot < 2; ot++) {
    const int o = wave * 32 + ot * 16 + row;
    const float sc = rsqrtf(var[o] + 1e-5f) * gamma[o];
    const float bi = beta[o] - mean[o] * sc;
    const size_t ob0 = (size_t)(n * O_ + o) * HW_ + hwb;
    f32x4 rv = *(const f32x4*)(xres + ob0);
    f32x4 ov;
#pragma unroll
    for (int r = 0; r < 4; r++) ov[r] = fmaxf(acc0[ot][r] * sc + bi + rv[r], 0.f);
    *(f32x4*)(out + ob0) = ov;
    const size_t ob1 = ob0 + 16;  // rows 16..31, same h-strip
    rv = *(const f32x4*)(xres + ob1);
#pragma unroll
    for (int r = 0; r < 4; r++) ov[r] = fmaxf(acc1[ot][r] * sc + bi + rv[r], 0.f);
    *(f32x4*)(out + ob1) = ov;
  }
}

extern "C" void kernel_launch(void* const* d_in, const int* in_sizes, int n_in,
                              void* d_out, int out_size, void* d_ws, size_t ws_size,
                              hipStream_t stream) {
  const float* x     = (const float*)d_in[0];
  const float* w_tm  = (const float*)d_in[2];
  const float* b_tm  = (const float*)d_in[3];
  const float* w_tr  = (const float*)d_in[4];
  const float* b_tr  = (const float*)d_in[5];
  const float* w_df  = (const float*)d_in[6];
  const float* gamma = (const float*)d_in[7];
  const float* beta  = (const float*)d_in[8];
  const float* mean  = (const float*)d_in[9];
  const float* var   = (const float*)d_in[10];
  float* out = (float*)d_out;

  char* ws = (char*)d_ws;
  unsigned short* xt    = (unsigned short*)(ws);                       //  9,437,184 B
  unsigned short* wfrag = (unsigned short*)(ws + 9437184);             //  1,179,648 B
  unsigned short* w6p   = (unsigned short*)(ws + 9437184 + 1179648);   //     73,728 B

  k_pre<<<720, 256, 0, stream>>>(x, w_df, w_tm, w_tr, xt, wfrag, w6p);
  k_fused<<<576, 512, 0, stream>>>(xt, wfrag, w6p, b_tm, b_tr, x,
                                   gamma, beta, mean, var, out);
}